// Round 2
// 169.889 us; speedup vs baseline: 1.0166x; 1.0166x over previous
//
#include <hip/hip_runtime.h>
#include <hip/hip_bf16.h>
#include <math.h>

// Problem constants (fixed by setup_inputs)
constexpr int B  = 4;
constexpr int Q  = 1024;
constexpr int D  = 256;
constexpr int NH = 8;
constexpr int NP = 4;
constexpr int H  = 128;
constexpr int W  = 128;
constexpr int HW = H * W;
constexpr int KAUG = 2112;          // 8*256 channels + 8 S + 56 zeros (K % 64 == 0)

typedef short   bf16x8  __attribute__((ext_vector_type(8)));
typedef float   f32x4   __attribute__((ext_vector_type(4)));
typedef short   short4v __attribute__((ext_vector_type(4)));
typedef unsigned short ushort8v __attribute__((ext_vector_type(8)));

__device__ inline unsigned short f2bf(float f) {
    union { float f; unsigned u; } v; v.f = f;
    unsigned r = v.u + 0x7fff + ((v.u >> 16) & 1);   // RNE
    return (unsigned short)(r >> 16);
}
__device__ inline float bf2f(unsigned short s) {
    union { unsigned u; float f; } v; v.u = ((unsigned)s) << 16;
    return v.f;
}

// async global->LDS, 16B per lane. LDS dest = wave-uniform base + lane*16.
__device__ inline void async16(const void* g, void* l) {
    __builtin_amdgcn_global_load_lds(
        (const __attribute__((address_space(1))) unsigned*)g,
        (__attribute__((address_space(3))) unsigned*)l, 16, 0, 0);
}

// ---------------------------------------------------------------------------
// STAGE 1 (role-merged; long-latency roles first — R9/R10 lesson).
//   [0, 128)      : raw = query @ [W_off|W_attn|0] + bias (fp32 SGEMM)
//   [128, 256)    : Wc_h = W_v @ W_out_h -> WcT, fp32 direct loads with
//                   in-kernel bf16 convert + LDS transpose (no Wout_t/Wv_bf!)
//   [256, 320)    : WcT border-correction cols 2048..2111 (b_v @ W_out_h)
//   [320, 4416)   : value fp32->bf16 (4096 elems/block)
//   [4416, 4420)  : spatial counting-sort of queries by reference point
//                   (16x16 buckets) -> perm, for stage-2 gather L2 locality
// ---------------------------------------------------------------------------
constexpr int R1_SG   = 0;
constexpr int R1_WC   = R1_SG + 128;                     // 128
constexpr int R1_BV   = R1_WC + 128;                     // 256
constexpr int R1_CONV = R1_BV + (D * 64) / 256;          // 320
constexpr int R1_END  = R1_CONV + (B * HW * D) / 4096;   // 4416
constexpr int R1_TOT  = R1_END + B;                      // 4420

__global__ __launch_bounds__(256)
void k_stage1(const float* __restrict__ value,
              const float* __restrict__ query,
              const float* __restrict__ W_off,  const float* __restrict__ b_off,
              const float* __restrict__ W_attn, const float* __restrict__ b_attn,
              const float* __restrict__ b_v,    const float* __restrict__ W_out,
              const float* __restrict__ W_v,
              const float* __restrict__ refpts,
              unsigned short* __restrict__ val_bf,
              float* __restrict__ raw,          // [B*Q, 128]
              unsigned short* __restrict__ WcT,
              int* __restrict__ perm) {         // [B*Q] sorted query order
    __shared__ __align__(16) unsigned char smemraw[16384];
    const int blk = blockIdx.x;
    const int tid = threadIdx.x;

    if (blk < R1_WC) {
        // --- fp32 SGEMM role: raw[M=4096, N=128] = query @ [W_off|W_attn|0] ---
        const int m0 = (blk >> 1) * 64;
        const int n0 = (blk & 1) * 64;
        float (*As)[68] = (float (*)[68])smemraw;
        float (*Bs)[68] = As + 16;
        const int tx = tid & 15, ty = tid >> 4;
        const int arow = tid >> 2, akg = (tid & 3) * 4;
        const int brow = tid >> 4, bcol = (tid & 15) * 4;

        float acc[4][4] = {};
        for (int k0 = 0; k0 < D; k0 += 16) {
            const float4 av = *(const float4*)&query[(size_t)(m0 + arow) * D + k0 + akg];
            const int kr = k0 + brow;
            const int j  = n0 + bcol;
            float4 bv;
            if (j < 64)      bv = *(const float4*)&W_off[kr * 64 + j];
            else if (j < 96) bv = *(const float4*)&W_attn[kr * 32 + (j - 64)];
            else             bv = (float4){0.f, 0.f, 0.f, 0.f};
            __syncthreads();
            As[akg + 0][arow] = av.x;
            As[akg + 1][arow] = av.y;
            As[akg + 2][arow] = av.z;
            As[akg + 3][arow] = av.w;
            *(float4*)&Bs[brow][bcol] = bv;
            __syncthreads();
            #pragma unroll
            for (int kk = 0; kk < 16; ++kk) {
                const float4 a = *(const float4*)&As[kk][ty * 4];
                const float4 b = *(const float4*)&Bs[kk][tx * 4];
                acc[0][0] += a.x * b.x; acc[0][1] += a.x * b.y; acc[0][2] += a.x * b.z; acc[0][3] += a.x * b.w;
                acc[1][0] += a.y * b.x; acc[1][1] += a.y * b.y; acc[1][2] += a.y * b.z; acc[1][3] += a.y * b.w;
                acc[2][0] += a.z * b.x; acc[2][1] += a.z * b.y; acc[2][2] += a.z * b.z; acc[2][3] += a.z * b.w;
                acc[3][0] += a.w * b.x; acc[3][1] += a.w * b.y; acc[3][2] += a.w * b.z; acc[3][3] += a.w * b.w;
            }
        }
        float bb[4];
        #pragma unroll
        for (int c = 0; c < 4; ++c) {
            const int col = n0 + tx * 4 + c;
            bb[c] = (col < 64) ? b_off[col] : ((col < 96) ? b_attn[col - 64] : 0.0f);
        }
        #pragma unroll
        for (int i = 0; i < 4; ++i) {
            const int m = m0 + ty * 4 + i;
            float4 r;
            r.x = acc[i][0] + bb[0];
            r.y = acc[i][1] + bb[1];
            r.z = acc[i][2] + bb[2];
            r.w = acc[i][3] + bb[3];
            *(float4*)&raw[(size_t)m * 128 + n0 + tx * 4] = r;
        }
    } else if (blk < R1_BV) {
        // --- Wc GEMM role: WcT[n0+n, z*256 + m0+m] = sum_i W_v[m][i] W_out[z*256+i][n]
        // fp32 global loads -> bf16 convert -> swizzled LDS -> MFMA.
        const int blkr = blk - R1_WC;
        const int z  = blkr >> 4;
        const int m0 = ((blkr >> 2) & 3) * 64;
        const int n0 = (blkr & 3) * 64;
        unsigned short* As = (unsigned short*)smemraw;       // 4096 shorts
        unsigned short* Bs = As + 4096;                      // 4096 shorts
        const int lane = tid & 63;
        const int w    = tid >> 6;
        const int wm   = w >> 1, wn = w & 1;

        int aoff[2][2], boff[2][2];
        #pragma unroll
        for (int i = 0; i < 2; ++i)
            #pragma unroll
            for (int kk = 0; kk < 2; ++kk) {
                const int ar = wm * 32 + i * 16 + (lane & 15);
                aoff[i][kk] = ar * 64 + ((((lane >> 4) + kk * 4) ^ (ar & 7)) * 8);
                const int br = wn * 32 + i * 16 + (lane & 15);
                boff[i][kk] = br * 64 + ((((lane >> 4) + kk * 4) ^ (br & 7)) * 8);
            }

        f32x4 acc[2][2];
        #pragma unroll
        for (int i = 0; i < 2; ++i)
            #pragma unroll
            for (int j = 0; j < 2; ++j) acc[i][j] = (f32x4){0.f, 0.f, 0.f, 0.f};

        for (int it = 0; it < 4; ++it) {       // K=256, BK=64
            const int k0 = it * 64;
            __syncthreads();                   // protect prev iter's frag reads
            // stage A (W_v rows m0..m0+63, cols k0..k0+63): 2 chunks/thread
            #pragma unroll
            for (int s = 0; s < 2; ++s) {
                const int cc = tid + s * 256;  // chunk id in [0,512)
                const int r = cc >> 3, c = cc & 7;
                const float4 v0 = *(const float4*)&W_v[(size_t)(m0 + r) * D + k0 + c * 8];
                const float4 v1 = *(const float4*)&W_v[(size_t)(m0 + r) * D + k0 + c * 8 + 4];
                ushort8v o;
                o[0] = f2bf(v0.x); o[1] = f2bf(v0.y); o[2] = f2bf(v0.z); o[3] = f2bf(v0.w);
                o[4] = f2bf(v1.x); o[5] = f2bf(v1.y); o[6] = f2bf(v1.z); o[7] = f2bf(v1.w);
                *(ushort8v*)&As[r * 64 + ((c ^ (r & 7)) * 8)] = o;
            }
            // stage B transposed: Bs[n][k] = W_out[z*256+k0+k][n0+n]
            {
                const int n = tid & 63, kseg = tid >> 6;
                float vj[16];
                #pragma unroll
                for (int j = 0; j < 16; ++j)
                    vj[j] = W_out[(size_t)(z * 256 + k0 + kseg * 16 + j) * D + n0 + n];
                #pragma unroll
                for (int jj = 0; jj < 2; ++jj) {
                    ushort8v o;
                    #pragma unroll
                    for (int q = 0; q < 8; ++q) o[q] = f2bf(vj[jj * 8 + q]);
                    const int c = kseg * 2 + jj;
                    *(ushort8v*)&Bs[n * 64 + ((c ^ (n & 7)) * 8)] = o;
                }
            }
            __syncthreads();
            bf16x8 af[2][2], bfv[2][2];
            #pragma unroll
            for (int i = 0; i < 2; ++i)
                #pragma unroll
                for (int kk = 0; kk < 2; ++kk) {
                    af[i][kk]  = *(const bf16x8*)&As[aoff[i][kk]];
                    bfv[i][kk] = *(const bf16x8*)&Bs[boff[i][kk]];
                }
            #pragma unroll
            for (int i = 0; i < 2; ++i)
                #pragma unroll
                for (int j = 0; j < 2; ++j)
                    #pragma unroll
                    for (int kk = 0; kk < 2; ++kk)
                        acc[i][j] = __builtin_amdgcn_mfma_f32_16x16x32_bf16(
                            af[i][kk], bfv[j][kk], acc[i][j], 0, 0, 0);
        }

        const int colb = n0 + wn * 32 + (lane & 15);
        const int rowb = m0 + wm * 32 + (lane >> 4) * 4;
        const int ocol = z * 256;
        #pragma unroll
        for (int j = 0; j < 2; ++j) {
            const int col = colb + j * 16;
            #pragma unroll
            for (int i = 0; i < 2; ++i)
                #pragma unroll
                for (int r = 0; r < 4; ++r)
                    WcT[(size_t)col * KAUG + ocol + rowb + i * 16 + r] =
                        f2bf(acc[i][j][r]);
        }
    } else if (blk < R1_CONV) {
        // --- WcT border-correction cols: WcT[n, 2048+c] = b_v . W_out[c*256.., n]
        const int t = (blk - R1_BV) * 256 + tid;      // n = t>>6, c = t&63
        const int n = t >> 6, c = t & 63;
        float v = 0.0f;
        if (c < 8) {
            #pragma unroll 8
            for (int j = 0; j < D; ++j)
                v += b_v[j] * W_out[((size_t)c * D + j) * D + n];
        }
        WcT[(size_t)n * KAUG + 2048 + c] = f2bf(v);
    } else if (blk < R1_END) {
        // --- value convert: 4096 elems per block (4 coalesced float4/thread)
        const int base = (blk - R1_CONV) * 4096;
        #pragma unroll
        for (int s = 0; s < 4; ++s) {
            const int i = base + s * 1024 + tid * 4;
            const float4 v = *(const float4*)&value[i];
            short4v o;
            o.x = (short)f2bf(v.x); o.y = (short)f2bf(v.y);
            o.z = (short)f2bf(v.z); o.w = (short)f2bf(v.w);
            *(short4v*)&val_bf[i] = o;
        }
    } else {
        // --- PERM role: counting-sort queries of batch b into 16x16 spatial
        // buckets by reference point. Sample locs are ref +- ~0.03 (offsets
        // are raw*0.1 with std~0.32), so bucket-ordered queries gather from
        // overlapping ~0.5MB image regions -> L2-resident stage-2 gather.
        // Output invariant: per-query math identical, only block order moves.
        const int b = blk - R1_END;
        __shared__ int cnt[256];
        __shared__ int scr[256];
        cnt[tid] = 0;
        __syncthreads();
        int bkt_l[4];
        #pragma unroll
        for (int s = 0; s < 4; ++s) {
            const int q = s * 256 + tid;
            const float2 rp = ((const float2*)refpts)[(size_t)b * 1024 + q];
            int bx = (int)(rp.x * 16.0f); bx = min(max(bx, 0), 15);
            int by = (int)(rp.y * 16.0f); by = min(max(by, 0), 15);
            bkt_l[s] = by * 16 + bx;
            atomicAdd(&cnt[bkt_l[s]], 1);
        }
        __syncthreads();
        // exclusive prefix sum over the 256 bucket counts (Hillis-Steele)
        const int run = cnt[tid];
        int incl = run;
        for (int off = 1; off < 256; off <<= 1) {
            scr[tid] = incl;
            __syncthreads();
            if (tid >= off) incl += scr[tid - off];
            __syncthreads();
        }
        cnt[tid] = incl - run;       // exclusive base, reused as cursor
        __syncthreads();
        #pragma unroll
        for (int s = 0; s < 4; ++s) {
            const int q = s * 256 + tid;
            const int pos = atomicAdd(&cnt[bkt_l[s]], 1);
            perm[b * 1024 + pos] = q;
        }
    }
}

// ---------------------------------------------------------------------------
// STAGE 2: pure sample — softmax + corner tables + gather (16 loads in
// flight) + point-reduce -> sv. One block per (b,q), 256 thr = 4 waves.
// Blocks walk queries in spatial-bucket order (perm) so concurrent blocks
// gather from overlapping image regions (L2-resident); sv rows are still
// written at the original bq position, so output is bitwise unchanged.
// ---------------------------------------------------------------------------
__global__ __launch_bounds__(256)
void k_stage2(const unsigned short* __restrict__ val,   // [B,H,W,D] bf16
              const float* __restrict__ raw,            // [B*Q,128]
              const float* __restrict__ refpts,         // [B,Q,2]
              const int* __restrict__ perm,             // [B*Q]
              unsigned short* __restrict__ sv) {        // [B*Q, KAUG]
    const int bi   = blockIdx.x;
    const int b    = bi >> 10;            // Q = 1024
    const int bq   = (b << 10) | perm[bi];
    const int tid  = threadIdx.x;
    const int lane = tid & 63;
    const int w    = tid >> 6;

    __shared__ float s_raw[128];
    __shared__ int   s_off[128];
    __shared__ float s_wgt[128];

    if (tid < 128) s_raw[tid] = raw[(size_t)bq * 128 + tid];
    __syncthreads();

    if (tid < NH * NP) {                  // tid == hp
        const int h = tid >> 2;
        float m = -1e30f;
        #pragma unroll
        for (int p = 0; p < NP; ++p) m = fmaxf(m, s_raw[64 + h * 4 + p]);
        float s = 0.0f;
        #pragma unroll
        for (int p = 0; p < NP; ++p) s += __expf(s_raw[64 + h * 4 + p] - m);
        const float a = __expf(s_raw[64 + tid] - m) / s;

        const float refx = refpts[(size_t)bq * 2 + 0];
        const float refy = refpts[(size_t)bq * 2 + 1];
        const float gx = fminf(fmaxf(refx + s_raw[tid * 2 + 0] * 0.1f, 0.0f), 1.0f) * 2.0f - 1.0f;
        const float gy = fminf(fmaxf(refy + s_raw[tid * 2 + 1] * 0.1f, 0.0f), 1.0f) * 2.0f - 1.0f;
        const float x  = ((gx + 1.0f) * (float)W - 1.0f) * 0.5f;
        const float y  = ((gy + 1.0f) * (float)H - 1.0f) * 0.5f;
        const float x0f = floorf(x), y0f = floorf(y);
        const float wx1 = x - x0f,  wy1 = y - y0f;
        const float wx0 = 1.0f - wx1, wy0 = 1.0f - wy1;
        const int x0 = (int)x0f, y0 = (int)y0f;
        const int x1 = x0 + 1,  y1 = y0 + 1;
        const float vx0 = (x0 >= 0 && x0 < W) ? 1.0f : 0.0f;
        const float vx1 = (x1 >= 0 && x1 < W) ? 1.0f : 0.0f;
        const float vy0 = (y0 >= 0 && y0 < H) ? 1.0f : 0.0f;
        const float vy1 = (y1 >= 0 && y1 < H) ? 1.0f : 0.0f;
        const int xc0 = min(max(x0, 0), W - 1);
        const int xc1 = min(max(x1, 0), W - 1);
        const int yc0 = min(max(y0, 0), H - 1);
        const int yc1 = min(max(y1, 0), H - 1);
        s_off[tid * 4 + 0] = yc0 * W + xc0;
        s_off[tid * 4 + 1] = yc0 * W + xc1;
        s_off[tid * 4 + 2] = yc1 * W + xc0;
        s_off[tid * 4 + 3] = yc1 * W + xc1;
        s_wgt[tid * 4 + 0] = a * wx0 * wy0 * vx0 * vy0;
        s_wgt[tid * 4 + 1] = a * wx1 * wy0 * vx1 * vy0;
        s_wgt[tid * 4 + 2] = a * wx0 * wy1 * vx0 * vy1;
        s_wgt[tid * 4 + 3] = a * wx1 * wy1 * vx1 * vy1;
    }
    __syncthreads();

    // augmented columns: S_h and zero padding
    if (tid < 8) {
        float S = 0.0f;
        #pragma unroll
        for (int c = 0; c < 16; ++c) S += s_wgt[tid * 16 + c];
        sv[(size_t)bq * KAUG + 2048 + tid] = f2bf(S);
    } else if (tid < 64) {
        sv[(size_t)bq * KAUG + 2048 + tid] = 0;
    }

    // gather: half-wave covers one pixel row (32 lanes x 8 ch = 512 B), each
    // wave-load fetches TWO corners; 16 loads issued back-to-back for MLP;
    // halves combined via shfl_xor(32).
    const int half = lane >> 5;
    const int l5   = lane & 31;
    const unsigned short* ib = val + (size_t)b * HW * D + l5 * 8;

    ushort8v vb[16];
    float    wg[16];
    #pragma unroll
    for (int j = 0; j < 16; ++j) {        // all 16 loads in flight
        const int flat = w * 32 + j * 2 + half;
        wg[j] = s_wgt[flat];
        vb[j] = *(const ushort8v*)(ib + (size_t)s_off[flat] * D);
    }

    float acc[2][8] = {};
    #pragma unroll
    for (int j = 0; j < 16; ++j) {
        const int g = j >> 3;             // head-within-wave
        #pragma unroll
        for (int k = 0; k < 8; ++k)
            acc[g][k] += wg[j] * bf2f(vb[j][k]);
    }

    #pragma unroll
    for (int hh = 0; hh < 2; ++hh) {
        float comb[8];
        #pragma unroll
        for (int k = 0; k < 8; ++k)
            comb[k] = acc[hh][k] + __shfl_xor(acc[hh][k], 32, 64);
        if (half == 0) {
            const int h = w * 2 + hh;
            ushort8v o;
            #pragma unroll
            for (int k = 0; k < 8; ++k) o[k] = f2bf(comb[k]);
            *(ushort8v*)&sv[(size_t)bq * KAUG + h * D + l5 * 8] = o;
        }
    }
}

// ---------------------------------------------------------------------------
// STAGE 3: out = sv @ WcT^T + b_out  (M=4096, N=256, K=2112)
// 32x64 tile, BK=64, double-buffered async16, grid (128,4) = 512 blocks
// -> 2 blocks/CU for latency hiding (R10: 64x64 grid 256 was 1 block/CU).
// 4 waves: wave w computes 32M x 16N (cols w*16..w*16+15).
// LDS: A dbuf 2x4KB + B dbuf 2x8KB = 24 KB.
// ---------------------------------------------------------------------------
__global__ __launch_bounds__(256)
void k_stage3(const unsigned short* __restrict__ sv,
              const unsigned short* __restrict__ WcT,
              const float* __restrict__ b_out,
              float* __restrict__ out) {
    __shared__ __align__(16) unsigned short lds[12288];  // [A0|B0|A1|B1] = 2k|4k|2k|4k

    const int tid  = threadIdx.x;
    const int lane = tid & 63;
    const int w    = tid >> 6;
    const int m0 = blockIdx.x * 32, n0 = blockIdx.y * 64;

    // staging: wave w stages A rows w*8+(lane>>3) (32 rows total) and B rows
    // same + same+32 (64 rows); chunk schk swizzled to match frag reads.
    const int srow = w * 8 + (lane >> 3);
    const int schk = (lane & 7) ^ (lane >> 3);
    const unsigned short* ag  = sv  + (size_t)(m0 + srow)      * KAUG + schk * 8;
    const unsigned short* bg0 = WcT + (size_t)(n0 + srow)      * KAUG + schk * 8;
    const unsigned short* bg1 = WcT + (size_t)(n0 + srow + 32) * KAUG + schk * 8;
    const int la = w * 512 + lane * 8;            // within A buf (2048 shorts)
    const int lb = la;                            // within B buf low half

    int aoff[2][2], boff[2];
    #pragma unroll
    for (int i = 0; i < 2; ++i)
        #pragma unroll
        for (int kk = 0; kk < 2; ++kk) {
            const int ar = i * 16 + (lane & 15);
            aoff[i][kk] = ar * 64 + ((((lane >> 4) + kk * 4) ^ (ar & 7)) * 8);
        }
    #pragma unroll
    for (int kk = 0; kk < 2; ++kk) {
        const int br = w * 16 + (lane & 15);
        boff[kk] = br * 64 + ((((lane >> 4) + kk * 4) ^ (br & 7)) * 8);
    }

    f32x4 acc[2];
    acc[0] = (f32x4){0.f, 0.f, 0.f, 0.f};
    acc[1] = (f32x4){0.f, 0.f, 0.f, 0.f};

    // buffers: A at stage*6144, B at stage*6144 + 2048
    async16(ag,  &lds[0 + la]);
    async16(bg0, &lds[2048 + lb]);
    async16(bg1, &lds[2048 + 2048 + lb]);

    const int niter = KAUG >> 6;                  // 33
    for (int it = 0; it < niter; ++it) {
        __syncthreads();
        const int cur = (it & 1) * 6144;
        if (it + 1 < niter) {
            const int nxt = 6144 - cur;
            const int ko  = (it + 1) * 64;
            async16(ag + ko,  &lds[nxt + la]);
            async16(bg0 + ko, &lds[nxt + 2048 + lb]);
            async16(bg1 + ko, &lds[nxt + 4096 + lb]);
        }
        bf16x8 af[2][2], bfv[2];
        #pragma unroll
        for (int kk = 0; kk < 2; ++kk) {
            bfv[kk] = *(const bf16x8*)&lds[cur + 2048 + boff[kk]];
            #pragma unroll
            for (int i = 0; i < 2; ++i)
                af[i][kk] = *(const bf16x8*)&lds[cur + aoff[i][kk]];
        }
        #pragma unroll
        for (int i = 0; i < 2; ++i)
            #pragma unroll
            for (int kk = 0; kk < 2; ++kk)
                acc[i] = __builtin_amdgcn_mfma_f32_16x16x32_bf16(
                    af[i][kk], bfv[kk], acc[i], 0, 0, 0);
    }

    const int col = n0 + w * 16 + (lane & 15);
    const float bb = b_out[col];
    const int rowb = m0 + (lane >> 4) * 4;
    #pragma unroll
    for (int i = 0; i < 2; ++i)
        #pragma unroll
        for (int r = 0; r < 4; ++r)
            out[(size_t)(rowb + i * 16 + r) * D + col] = acc[i][r] + bb;
}

// ---------------------------------------------------------------------------
extern "C" void kernel_launch(void* const* d_in, const int* in_sizes, int n_in,
                              void* d_out, int out_size, void* d_ws, size_t ws_size,
                              hipStream_t stream) {
    const float* query  = (const float*)d_in[0];
    const float* refpts = (const float*)d_in[1];
    const float* value  = (const float*)d_in[2];
    const float* W_off  = (const float*)d_in[3];
    const float* b_off  = (const float*)d_in[4];
    const float* W_attn = (const float*)d_in[5];
    const float* b_attn = (const float*)d_in[6];
    const float* W_v    = (const float*)d_in[7];
    const float* b_v    = (const float*)d_in[8];
    const float* W_out  = (const float*)d_in[9];
    const float* b_out  = (const float*)d_in[10];
    float* out = (float*)d_out;

    // workspace layout (byte offsets, all 256B aligned)
    char* wsb = (char*)d_ws;
    unsigned short* val_bf = (unsigned short*)(wsb);             // 33,554,432 B
    unsigned short* sv     = (unsigned short*)(wsb + 33554432);  // 17,301,504 B
    unsigned short* WcT    = (unsigned short*)(wsb + 50855936);  //  1,081,344 B
    float*          raw    = (float*)(wsb + 51937280);           //  2,097,152 B
    int*            perm   = (int*)(wsb + 54034432);             //     16,384 B

    // 1: raw-SGEMM | Wc GEMM (fp32 in) | b_v cols | value conv | query sort
    k_stage1<<<R1_TOT, 256, 0, stream>>>(value, query, W_off, b_off,
                                         W_attn, b_attn, b_v, W_out, W_v,
                                         refpts, val_bf, raw, WcT, perm);

    // 2: sample -> sv (bucket-ordered via perm)
    k_stage2<<<B * Q, 256, 0, stream>>>(val_bf, raw, refpts, perm, sv);

    // 3: out = sv @ WcT^T + b_out
    {
        dim3 grid((B * Q) / 32, D / 64);
        k_stage3<<<grid, 256, 0, stream>>>(sv, WcT, b_out, out);
    }
}

// Round 3
// 164.144 us; speedup vs baseline: 1.0522x; 1.0350x over previous
//
#include <hip/hip_runtime.h>
#include <hip/hip_bf16.h>
#include <math.h>

// Problem constants (fixed by setup_inputs)
constexpr int B  = 4;
constexpr int Q  = 1024;
constexpr int D  = 256;
constexpr int NH = 8;
constexpr int NP = 4;
constexpr int H  = 128;
constexpr int W  = 128;
constexpr int HW = H * W;
constexpr int KAUG = 2112;          // 8*256 channels + 8 S + 56 zeros (K % 64 == 0)

typedef short   bf16x8  __attribute__((ext_vector_type(8)));
typedef float   f32x4   __attribute__((ext_vector_type(4)));
typedef short   short4v __attribute__((ext_vector_type(4)));
typedef unsigned short ushort8v __attribute__((ext_vector_type(8)));

__device__ inline unsigned short f2bf(float f) {
    union { float f; unsigned u; } v; v.f = f;
    unsigned r = v.u + 0x7fff + ((v.u >> 16) & 1);   // RNE
    return (unsigned short)(r >> 16);
}
__device__ inline float bf2f(unsigned short s) {
    union { unsigned u; float f; } v; v.u = ((unsigned)s) << 16;
    return v.f;
}

// async global->LDS, 16B per lane. LDS dest = wave-uniform base + lane*16.
__device__ inline void async16(const void* g, void* l) {
    __builtin_amdgcn_global_load_lds(
        (const __attribute__((address_space(1))) unsigned*)g,
        (__attribute__((address_space(3))) unsigned*)l, 16, 0, 0);
}

// ---------------------------------------------------------------------------
// STAGE 1 (role-merged; long-latency roles first — R9/R10 lesson).
//   [0, 128)      : raw = query @ [W_off|W_attn|0] + bias (fp32 SGEMM)
//   [128, 256)    : Wc_h = W_v @ W_out_h -> WcT, fp32 direct loads with
//                   in-kernel bf16 convert + LDS transpose (no Wout_t/Wv_bf!)
//   [256, 320)    : WcT border-correction cols 2048..2111 (b_v @ W_out_h)
//   [320, 4416)   : value fp32->bf16 (4096 elems/block)
//   [4416, 4420)  : spatial counting-sort of queries by reference point
//                   (16x16 buckets) -> perm, for stage-2 gather L2 locality
// ---------------------------------------------------------------------------
constexpr int R1_SG   = 0;
constexpr int R1_WC   = R1_SG + 128;                     // 128
constexpr int R1_BV   = R1_WC + 128;                     // 256
constexpr int R1_CONV = R1_BV + (D * 64) / 256;          // 320
constexpr int R1_END  = R1_CONV + (B * HW * D) / 4096;   // 4416
constexpr int R1_TOT  = R1_END + B;                      // 4420

__global__ __launch_bounds__(256)
void k_stage1(const float* __restrict__ value,
              const float* __restrict__ query,
              const float* __restrict__ W_off,  const float* __restrict__ b_off,
              const float* __restrict__ W_attn, const float* __restrict__ b_attn,
              const float* __restrict__ b_v,    const float* __restrict__ W_out,
              const float* __restrict__ W_v,
              const float* __restrict__ refpts,
              unsigned short* __restrict__ val_bf,
              float* __restrict__ raw,          // [B*Q, 128]
              unsigned short* __restrict__ WcT,
              int* __restrict__ perm) {         // [B*Q] sorted query order
    __shared__ __align__(16) unsigned char smemraw[16384];
    const int blk = blockIdx.x;
    const int tid = threadIdx.x;

    if (blk < R1_WC) {
        // --- fp32 SGEMM role: raw[M=4096, N=128] = query @ [W_off|W_attn|0] ---
        const int m0 = (blk >> 1) * 64;
        const int n0 = (blk & 1) * 64;
        float (*As)[68] = (float (*)[68])smemraw;
        float (*Bs)[68] = As + 16;
        const int tx = tid & 15, ty = tid >> 4;
        const int arow = tid >> 2, akg = (tid & 3) * 4;
        const int brow = tid >> 4, bcol = (tid & 15) * 4;

        float acc[4][4] = {};
        for (int k0 = 0; k0 < D; k0 += 16) {
            const float4 av = *(const float4*)&query[(size_t)(m0 + arow) * D + k0 + akg];
            const int kr = k0 + brow;
            const int j  = n0 + bcol;
            float4 bv;
            if (j < 64)      bv = *(const float4*)&W_off[kr * 64 + j];
            else if (j < 96) bv = *(const float4*)&W_attn[kr * 32 + (j - 64)];
            else             bv = (float4){0.f, 0.f, 0.f, 0.f};
            __syncthreads();
            As[akg + 0][arow] = av.x;
            As[akg + 1][arow] = av.y;
            As[akg + 2][arow] = av.z;
            As[akg + 3][arow] = av.w;
            *(float4*)&Bs[brow][bcol] = bv;
            __syncthreads();
            #pragma unroll
            for (int kk = 0; kk < 16; ++kk) {
                const float4 a = *(const float4*)&As[kk][ty * 4];
                const float4 b = *(const float4*)&Bs[kk][tx * 4];
                acc[0][0] += a.x * b.x; acc[0][1] += a.x * b.y; acc[0][2] += a.x * b.z; acc[0][3] += a.x * b.w;
                acc[1][0] += a.y * b.x; acc[1][1] += a.y * b.y; acc[1][2] += a.y * b.z; acc[1][3] += a.y * b.w;
                acc[2][0] += a.z * b.x; acc[2][1] += a.z * b.y; acc[2][2] += a.z * b.z; acc[2][3] += a.z * b.w;
                acc[3][0] += a.w * b.x; acc[3][1] += a.w * b.y; acc[3][2] += a.w * b.z; acc[3][3] += a.w * b.w;
            }
        }
        float bb[4];
        #pragma unroll
        for (int c = 0; c < 4; ++c) {
            const int col = n0 + tx * 4 + c;
            bb[c] = (col < 64) ? b_off[col] : ((col < 96) ? b_attn[col - 64] : 0.0f);
        }
        #pragma unroll
        for (int i = 0; i < 4; ++i) {
            const int m = m0 + ty * 4 + i;
            float4 r;
            r.x = acc[i][0] + bb[0];
            r.y = acc[i][1] + bb[1];
            r.z = acc[i][2] + bb[2];
            r.w = acc[i][3] + bb[3];
            *(float4*)&raw[(size_t)m * 128 + n0 + tx * 4] = r;
        }
    } else if (blk < R1_BV) {
        // --- Wc GEMM role: WcT[n0+n, z*256 + m0+m] = sum_i W_v[m][i] W_out[z*256+i][n]
        // fp32 global loads -> bf16 convert -> swizzled LDS -> MFMA.
        const int blkr = blk - R1_WC;
        const int z  = blkr >> 4;
        const int m0 = ((blkr >> 2) & 3) * 64;
        const int n0 = (blkr & 3) * 64;
        unsigned short* As = (unsigned short*)smemraw;       // 4096 shorts
        unsigned short* Bs = As + 4096;                      // 4096 shorts
        const int lane = tid & 63;
        const int w    = tid >> 6;
        const int wm   = w >> 1, wn = w & 1;

        int aoff[2][2], boff[2][2];
        #pragma unroll
        for (int i = 0; i < 2; ++i)
            #pragma unroll
            for (int kk = 0; kk < 2; ++kk) {
                const int ar = wm * 32 + i * 16 + (lane & 15);
                aoff[i][kk] = ar * 64 + ((((lane >> 4) + kk * 4) ^ (ar & 7)) * 8);
                const int br = wn * 32 + i * 16 + (lane & 15);
                boff[i][kk] = br * 64 + ((((lane >> 4) + kk * 4) ^ (br & 7)) * 8);
            }

        f32x4 acc[2][2];
        #pragma unroll
        for (int i = 0; i < 2; ++i)
            #pragma unroll
            for (int j = 0; j < 2; ++j) acc[i][j] = (f32x4){0.f, 0.f, 0.f, 0.f};

        for (int it = 0; it < 4; ++it) {       // K=256, BK=64
            const int k0 = it * 64;
            __syncthreads();                   // protect prev iter's frag reads
            // stage A (W_v rows m0..m0+63, cols k0..k0+63): 2 chunks/thread
            #pragma unroll
            for (int s = 0; s < 2; ++s) {
                const int cc = tid + s * 256;  // chunk id in [0,512)
                const int r = cc >> 3, c = cc & 7;
                const float4 v0 = *(const float4*)&W_v[(size_t)(m0 + r) * D + k0 + c * 8];
                const float4 v1 = *(const float4*)&W_v[(size_t)(m0 + r) * D + k0 + c * 8 + 4];
                ushort8v o;
                o[0] = f2bf(v0.x); o[1] = f2bf(v0.y); o[2] = f2bf(v0.z); o[3] = f2bf(v0.w);
                o[4] = f2bf(v1.x); o[5] = f2bf(v1.y); o[6] = f2bf(v1.z); o[7] = f2bf(v1.w);
                *(ushort8v*)&As[r * 64 + ((c ^ (r & 7)) * 8)] = o;
            }
            // stage B transposed: Bs[n][k] = W_out[z*256+k0+k][n0+n]
            {
                const int n = tid & 63, kseg = tid >> 6;
                float vj[16];
                #pragma unroll
                for (int j = 0; j < 16; ++j)
                    vj[j] = W_out[(size_t)(z * 256 + k0 + kseg * 16 + j) * D + n0 + n];
                #pragma unroll
                for (int jj = 0; jj < 2; ++jj) {
                    ushort8v o;
                    #pragma unroll
                    for (int q = 0; q < 8; ++q) o[q] = f2bf(vj[jj * 8 + q]);
                    const int c = kseg * 2 + jj;
                    *(ushort8v*)&Bs[n * 64 + ((c ^ (n & 7)) * 8)] = o;
                }
            }
            __syncthreads();
            bf16x8 af[2][2], bfv[2][2];
            #pragma unroll
            for (int i = 0; i < 2; ++i)
                #pragma unroll
                for (int kk = 0; kk < 2; ++kk) {
                    af[i][kk]  = *(const bf16x8*)&As[aoff[i][kk]];
                    bfv[i][kk] = *(const bf16x8*)&Bs[boff[i][kk]];
                }
            #pragma unroll
            for (int i = 0; i < 2; ++i)
                #pragma unroll
                for (int j = 0; j < 2; ++j)
                    #pragma unroll
                    for (int kk = 0; kk < 2; ++kk)
                        acc[i][j] = __builtin_amdgcn_mfma_f32_16x16x32_bf16(
                            af[i][kk], bfv[j][kk], acc[i][j], 0, 0, 0);
        }

        const int colb = n0 + wn * 32 + (lane & 15);
        const int rowb = m0 + wm * 32 + (lane >> 4) * 4;
        const int ocol = z * 256;
        #pragma unroll
        for (int j = 0; j < 2; ++j) {
            const int col = colb + j * 16;
            #pragma unroll
            for (int i = 0; i < 2; ++i)
                #pragma unroll
                for (int r = 0; r < 4; ++r)
                    WcT[(size_t)col * KAUG + ocol + rowb + i * 16 + r] =
                        f2bf(acc[i][j][r]);
        }
    } else if (blk < R1_CONV) {
        // --- WcT border-correction cols: WcT[n, 2048+c] = b_v . W_out[c*256.., n]
        const int t = (blk - R1_BV) * 256 + tid;      // n = t>>6, c = t&63
        const int n = t >> 6, c = t & 63;
        float v = 0.0f;
        if (c < 8) {
            #pragma unroll 8
            for (int j = 0; j < D; ++j)
                v += b_v[j] * W_out[((size_t)c * D + j) * D + n];
        }
        WcT[(size_t)n * KAUG + 2048 + c] = f2bf(v);
    } else if (blk < R1_END) {
        // --- value convert: 4096 elems per block (4 coalesced float4/thread)
        const int base = (blk - R1_CONV) * 4096;
        #pragma unroll
        for (int s = 0; s < 4; ++s) {
            const int i = base + s * 1024 + tid * 4;
            const float4 v = *(const float4*)&value[i];
            short4v o;
            o.x = (short)f2bf(v.x); o.y = (short)f2bf(v.y);
            o.z = (short)f2bf(v.z); o.w = (short)f2bf(v.w);
            *(short4v*)&val_bf[i] = o;
        }
    } else {
        // --- PERM role: counting-sort queries of batch b into 16x16 spatial
        // buckets by reference point. Sample locs are ref +- ~12px, so
        // bucket-ordered queries gather from overlapping image regions.
        // Output invariant: per-query math identical, only block order moves.
        const int b = blk - R1_END;
        __shared__ int cnt[256];
        __shared__ int scr[256];
        cnt[tid] = 0;
        __syncthreads();
        int bkt_l[4];
        #pragma unroll
        for (int s = 0; s < 4; ++s) {
            const int q = s * 256 + tid;
            const float2 rp = ((const float2*)refpts)[(size_t)b * 1024 + q];
            int bx = (int)(rp.x * 16.0f); bx = min(max(bx, 0), 15);
            int by = (int)(rp.y * 16.0f); by = min(max(by, 0), 15);
            bkt_l[s] = by * 16 + bx;
            atomicAdd(&cnt[bkt_l[s]], 1);
        }
        __syncthreads();
        // exclusive prefix sum over the 256 bucket counts (Hillis-Steele)
        const int run = cnt[tid];
        int incl = run;
        for (int off = 1; off < 256; off <<= 1) {
            scr[tid] = incl;
            __syncthreads();
            if (tid >= off) incl += scr[tid - off];
            __syncthreads();
        }
        cnt[tid] = incl - run;       // exclusive base, reused as cursor
        __syncthreads();
        #pragma unroll
        for (int s = 0; s < 4; ++s) {
            const int q = s * 256 + tid;
            const int pos = atomicAdd(&cnt[bkt_l[s]], 1);
            perm[b * 1024 + pos] = q;
        }
    }
}

// ---------------------------------------------------------------------------
// STAGE 2: pure sample — softmax + corner tables + gather (16 loads in
// flight) + point-reduce -> sv. One block per (b,q), 256 thr = 4 waves.
// Block order: XCD-chunked (bid&7 -> chunk of 512 consecutive sorted
// positions) so each XCD's ~64 concurrent blocks cover ~4 adjacent spatial
// buckets (~1MB image region, L2-resident); round-robin would dilute the
// perm-sort locality 8x across the per-XCD L2s. sv rows still written at
// the original bq position -> output bitwise unchanged.
// ---------------------------------------------------------------------------
__global__ __launch_bounds__(256)
void k_stage2(const unsigned short* __restrict__ val,   // [B,H,W,D] bf16
              const float* __restrict__ raw,            // [B*Q,128]
              const float* __restrict__ refpts,         // [B,Q,2]
              const int* __restrict__ perm,             // [B*Q]
              unsigned short* __restrict__ sv) {        // [B*Q, KAUG]
    const int bi0  = blockIdx.x;
    const int bi   = (bi0 & 7) * 512 + (bi0 >> 3);   // XCD-chunked, bijective (4096 = 8*512)
    const int b    = bi >> 10;            // Q = 1024
    const int bq   = (b << 10) | perm[bi];
    const int tid  = threadIdx.x;
    const int lane = tid & 63;
    const int w    = tid >> 6;

    __shared__ float s_raw[128];
    __shared__ int   s_off[128];
    __shared__ float s_wgt[128];

    if (tid < 128) s_raw[tid] = raw[(size_t)bq * 128 + tid];
    __syncthreads();

    if (tid < NH * NP) {                  // tid == hp
        const int h = tid >> 2;
        float m = -1e30f;
        #pragma unroll
        for (int p = 0; p < NP; ++p) m = fmaxf(m, s_raw[64 + h * 4 + p]);
        float s = 0.0f;
        #pragma unroll
        for (int p = 0; p < NP; ++p) s += __expf(s_raw[64 + h * 4 + p] - m);
        const float a = __expf(s_raw[64 + tid] - m) / s;

        const float refx = refpts[(size_t)bq * 2 + 0];
        const float refy = refpts[(size_t)bq * 2 + 1];
        const float gx = fminf(fmaxf(refx + s_raw[tid * 2 + 0] * 0.1f, 0.0f), 1.0f) * 2.0f - 1.0f;
        const float gy = fminf(fmaxf(refy + s_raw[tid * 2 + 1] * 0.1f, 0.0f), 1.0f) * 2.0f - 1.0f;
        const float x  = ((gx + 1.0f) * (float)W - 1.0f) * 0.5f;
        const float y  = ((gy + 1.0f) * (float)H - 1.0f) * 0.5f;
        const float x0f = floorf(x), y0f = floorf(y);
        const float wx1 = x - x0f,  wy1 = y - y0f;
        const float wx0 = 1.0f - wx1, wy0 = 1.0f - wy1;
        const int x0 = (int)x0f, y0 = (int)y0f;
        const int x1 = x0 + 1,  y1 = y0 + 1;
        const float vx0 = (x0 >= 0 && x0 < W) ? 1.0f : 0.0f;
        const float vx1 = (x1 >= 0 && x1 < W) ? 1.0f : 0.0f;
        const float vy0 = (y0 >= 0 && y0 < H) ? 1.0f : 0.0f;
        const float vy1 = (y1 >= 0 && y1 < H) ? 1.0f : 0.0f;
        const int xc0 = min(max(x0, 0), W - 1);
        const int xc1 = min(max(x1, 0), W - 1);
        const int yc0 = min(max(y0, 0), H - 1);
        const int yc1 = min(max(y1, 0), H - 1);
        s_off[tid * 4 + 0] = yc0 * W + xc0;
        s_off[tid * 4 + 1] = yc0 * W + xc1;
        s_off[tid * 4 + 2] = yc1 * W + xc0;
        s_off[tid * 4 + 3] = yc1 * W + xc1;
        s_wgt[tid * 4 + 0] = a * wx0 * wy0 * vx0 * vy0;
        s_wgt[tid * 4 + 1] = a * wx1 * wy0 * vx1 * vy0;
        s_wgt[tid * 4 + 2] = a * wx0 * wy1 * vx0 * vy1;
        s_wgt[tid * 4 + 3] = a * wx1 * wy1 * vx1 * vy1;
    }
    __syncthreads();

    // augmented columns: S_h and zero padding
    if (tid < 8) {
        float S = 0.0f;
        #pragma unroll
        for (int c = 0; c < 16; ++c) S += s_wgt[tid * 16 + c];
        sv[(size_t)bq * KAUG + 2048 + tid] = f2bf(S);
    } else if (tid < 64) {
        sv[(size_t)bq * KAUG + 2048 + tid] = 0;
    }

    // gather: half-wave covers one pixel row (32 lanes x 8 ch = 512 B), each
    // wave-load fetches TWO corners; 16 loads issued back-to-back for MLP;
    // halves combined via shfl_xor(32).
    const int half = lane >> 5;
    const int l5   = lane & 31;
    const unsigned short* ib = val + (size_t)b * HW * D + l5 * 8;

    ushort8v vb[16];
    float    wg[16];
    #pragma unroll
    for (int j = 0; j < 16; ++j) {        // all 16 loads in flight
        const int flat = w * 32 + j * 2 + half;
        wg[j] = s_wgt[flat];
        vb[j] = *(const ushort8v*)(ib + (size_t)s_off[flat] * D);
    }

    float acc[2][8] = {};
    #pragma unroll
    for (int j = 0; j < 16; ++j) {
        const int g = j >> 3;             // head-within-wave
        #pragma unroll
        for (int k = 0; k < 8; ++k)
            acc[g][k] += wg[j] * bf2f(vb[j][k]);
    }

    #pragma unroll
    for (int hh = 0; hh < 2; ++hh) {
        float comb[8];
        #pragma unroll
        for (int k = 0; k < 8; ++k)
            comb[k] = acc[hh][k] + __shfl_xor(acc[hh][k], 32, 64);
        if (half == 0) {
            const int h = w * 2 + hh;
            ushort8v o;
            #pragma unroll
            for (int k = 0; k < 8; ++k) o[k] = f2bf(comb[k]);
            *(ushort8v*)&sv[(size_t)bq * KAUG + h * D + l5 * 8] = o;
        }
    }
}

// ---------------------------------------------------------------------------
// STAGE 3: out = sv @ WcT^T + b_out  (M=4096, N=256, K=2112)
// 32x64 tile, BK=64, double-buffered async16, 512 linear blocks
// -> 2 blocks/CU for latency hiding.
// Tile decode is N-fastest + XCD-chunked: each XCD runs 16 M-tiles x all 4
// N-tiles consecutively, so an M-tile's sv rows are fetched into its L2
// once and reused by 4 N-tiles from L2 instead of 4x from L3 (~52MB saved).
// 4 waves: wave w computes 32M x 16N (cols w*16..w*16+15).
// LDS: A dbuf 2x4KB + B dbuf 2x8KB = 24 KB.
// ---------------------------------------------------------------------------
__global__ __launch_bounds__(256)
void k_stage3(const unsigned short* __restrict__ sv,
              const unsigned short* __restrict__ WcT,
              const float* __restrict__ b_out,
              float* __restrict__ out) {
    __shared__ __align__(16) unsigned short lds[12288];  // [A0|B0|A1|B1] = 2k|4k|2k|4k

    const int tid  = threadIdx.x;
    const int lane = tid & 63;
    const int w    = tid >> 6;
    const int sid  = (blockIdx.x & 7) * 64 + (blockIdx.x >> 3);  // XCD-chunked (512 = 8*64)
    const int m0   = (sid >> 2) * 32;          // 128 M-tiles
    const int n0   = (sid & 3) * 64;           // 4 N-tiles, N-fastest per M-tile

    // staging: wave w stages A rows w*8+(lane>>3) (32 rows total) and B rows
    // same + same+32 (64 rows); chunk schk swizzled to match frag reads.
    const int srow = w * 8 + (lane >> 3);
    const int schk = (lane & 7) ^ (lane >> 3);
    const unsigned short* ag  = sv  + (size_t)(m0 + srow)      * KAUG + schk * 8;
    const unsigned short* bg0 = WcT + (size_t)(n0 + srow)      * KAUG + schk * 8;
    const unsigned short* bg1 = WcT + (size_t)(n0 + srow + 32) * KAUG + schk * 8;
    const int la = w * 512 + lane * 8;            // within A buf (2048 shorts)
    const int lb = la;                            // within B buf low half

    int aoff[2][2], boff[2];
    #pragma unroll
    for (int i = 0; i < 2; ++i)
        #pragma unroll
        for (int kk = 0; kk < 2; ++kk) {
            const int ar = i * 16 + (lane & 15);
            aoff[i][kk] = ar * 64 + ((((lane >> 4) + kk * 4) ^ (ar & 7)) * 8);
        }
    #pragma unroll
    for (int kk = 0; kk < 2; ++kk) {
        const int br = w * 16 + (lane & 15);
        boff[kk] = br * 64 + ((((lane >> 4) + kk * 4) ^ (br & 7)) * 8);
    }

    f32x4 acc[2];
    acc[0] = (f32x4){0.f, 0.f, 0.f, 0.f};
    acc[1] = (f32x4){0.f, 0.f, 0.f, 0.f};

    // buffers: A at stage*6144, B at stage*6144 + 2048
    async16(ag,  &lds[0 + la]);
    async16(bg0, &lds[2048 + lb]);
    async16(bg1, &lds[2048 + 2048 + lb]);

    const int niter = KAUG >> 6;                  // 33
    for (int it = 0; it < niter; ++it) {
        __syncthreads();
        const int cur = (it & 1) * 6144;
        if (it + 1 < niter) {
            const int nxt = 6144 - cur;
            const int ko  = (it + 1) * 64;
            async16(ag + ko,  &lds[nxt + la]);
            async16(bg0 + ko, &lds[nxt + 2048 + lb]);
            async16(bg1 + ko, &lds[nxt + 4096 + lb]);
        }
        bf16x8 af[2][2], bfv[2];
        #pragma unroll
        for (int kk = 0; kk < 2; ++kk) {
            bfv[kk] = *(const bf16x8*)&lds[cur + 2048 + boff[kk]];
            #pragma unroll
            for (int i = 0; i < 2; ++i)
                af[i][kk] = *(const bf16x8*)&lds[cur + aoff[i][kk]];
        }
        #pragma unroll
        for (int i = 0; i < 2; ++i)
            #pragma unroll
            for (int kk = 0; kk < 2; ++kk)
                acc[i] = __builtin_amdgcn_mfma_f32_16x16x32_bf16(
                    af[i][kk], bfv[kk], acc[i], 0, 0, 0);
    }

    const int col = n0 + w * 16 + (lane & 15);
    const float bb = b_out[col];
    const int rowb = m0 + (lane >> 4) * 4;
    #pragma unroll
    for (int i = 0; i < 2; ++i)
        #pragma unroll
        for (int r = 0; r < 4; ++r)
            out[(size_t)(rowb + i * 16 + r) * D + col] = acc[i][r] + bb;
}

// ---------------------------------------------------------------------------
extern "C" void kernel_launch(void* const* d_in, const int* in_sizes, int n_in,
                              void* d_out, int out_size, void* d_ws, size_t ws_size,
                              hipStream_t stream) {
    const float* query  = (const float*)d_in[0];
    const float* refpts = (const float*)d_in[1];
    const float* value  = (const float*)d_in[2];
    const float* W_off  = (const float*)d_in[3];
    const float* b_off  = (const float*)d_in[4];
    const float* W_attn = (const float*)d_in[5];
    const float* b_attn = (const float*)d_in[6];
    const float* W_v    = (const float*)d_in[7];
    const float* b_v    = (const float*)d_in[8];
    const float* W_out  = (const float*)d_in[9];
    const float* b_out  = (const float*)d_in[10];
    float* out = (float*)d_out;

    // workspace layout (byte offsets, all 256B aligned)
    char* wsb = (char*)d_ws;
    unsigned short* val_bf = (unsigned short*)(wsb);             // 33,554,432 B
    unsigned short* sv     = (unsigned short*)(wsb + 33554432);  // 17,301,504 B
    unsigned short* WcT    = (unsigned short*)(wsb + 50855936);  //  1,081,344 B
    float*          raw    = (float*)(wsb + 51937280);           //  2,097,152 B
    int*            perm   = (int*)(wsb + 54034432);             //     16,384 B

    // 1: raw-SGEMM | Wc GEMM (fp32 in) | b_v cols | value conv | query sort
    k_stage1<<<R1_TOT, 256, 0, stream>>>(value, query, W_off, b_off,
                                         W_attn, b_attn, b_v, W_out, W_v,
                                         refpts, val_bf, raw, WcT, perm);

    // 2: sample -> sv (bucket-ordered via perm, XCD-chunked)
    k_stage2<<<B * Q, 256, 0, stream>>>(val_bf, raw, refpts, perm, sv);

    // 3: out = sv @ WcT^T + b_out (XCD-chunked, N-fastest)
    k_stage3<<<512, 256, 0, stream>>>(sv, WcT, b_out, out);
}